// Round 1
// baseline (1499.344 us; speedup 1.0000x reference)
//
#include <hip/hip_runtime.h>

// ---------------- CSR build kernels ----------------

__global__ void zero_k(int* p, int n) {
    int i = blockIdx.x * 256 + threadIdx.x;
    if (i < n) p[i] = 0;
}

__global__ void hist_k(const int* __restrict__ dst, int E, int* __restrict__ deg) {
    int i = blockIdx.x * 256 + threadIdx.x;
    if (i < E) atomicAdd(&deg[dst[i]], 1);
}

__global__ void scan_pass1(const int* __restrict__ deg, int n, int* __restrict__ bsum) {
    __shared__ int s[256];
    int i = blockIdx.x * 256 + threadIdx.x;
    int v = (i < n) ? deg[i] : 0;
    s[threadIdx.x] = v;
    __syncthreads();
    for (int off = 128; off > 0; off >>= 1) {
        if (threadIdx.x < off) s[threadIdx.x] += s[threadIdx.x + off];
        __syncthreads();
    }
    if (threadIdx.x == 0) bsum[blockIdx.x] = s[0];
}

// single block, 512 threads: exclusive scan of bsum[0..nb), nb <= 512
__global__ void scan_pass2(int* bsum, int nb) {
    __shared__ int s[512];
    int t = threadIdx.x;
    int v = (t < nb) ? bsum[t] : 0;
    s[t] = v;
    __syncthreads();
    for (int off = 1; off < 512; off <<= 1) {
        int x = (t >= off) ? s[t - off] : 0;
        __syncthreads();
        s[t] += x;
        __syncthreads();
    }
    if (t < nb) bsum[t] = s[t] - v;
}

__global__ void scan_pass3(const int* __restrict__ deg, int n, const int* __restrict__ bsum,
                           int* __restrict__ roff) {
    __shared__ int s[256];
    int t = threadIdx.x;
    int i = blockIdx.x * 256 + t;
    int v = (i < n) ? deg[i] : 0;
    s[t] = v;
    __syncthreads();
    for (int off = 1; off < 256; off <<= 1) {
        int x = (t >= off) ? s[t - off] : 0;
        __syncthreads();
        s[t] += x;
        __syncthreads();
    }
    int excl = s[t] - v;
    int res = bsum[blockIdx.x] + excl;
    if (i < n) roff[i] = res;
    if (i == n - 1) roff[n] = res + v;
}

__global__ void scatter_k(const int* __restrict__ src, const int* __restrict__ dst, int E,
                          const int* __restrict__ roff, int* __restrict__ cur,
                          int* __restrict__ csrc) {
    int i = blockIdx.x * 256 + threadIdx.x;
    if (i < E) {
        int d = dst[i];
        int pos = roff[d] + atomicAdd(&cur[d], 1);
        csrc[pos] = src[i];
    }
}

// ---------------- compute kernels ----------------

__global__ void combine_wb_k(const float* __restrict__ Wa, const float* __restrict__ Wb,
                             const float* __restrict__ ba, const float* __restrict__ bb,
                             float* __restrict__ Wo, float* __restrict__ bo) {
    int i = blockIdx.x * 256 + threadIdx.x;
    if (i < 128 * 128) Wo[i] = Wa[i] + Wb[i];
    if (i < 128) bo[i] = ba[i] + bb[i];
}

// C[N x 128] = A[N x 128] @ W[128 x 128] (+ bias). Block: 256 threads, 32 rows/block.
__global__ __launch_bounds__(256) void gemm128_k(const float* __restrict__ A, int N,
                                                 const float* __restrict__ W,
                                                 const float* __restrict__ bias,
                                                 float* __restrict__ C) {
    __shared__ float As[32][132];
    int t = threadIdx.x;
    int col = t & 127, half = t >> 7;
    int row0 = blockIdx.x * 32;
    const float4* A4 = (const float4*)A;
    for (int l = t; l < 1024; l += 256) {
        int r = l >> 5, q = l & 31;
        int gr = row0 + r;
        float4 v = make_float4(0.f, 0.f, 0.f, 0.f);
        if (gr < N) v = A4[(size_t)gr * 32 + q];
        As[r][q * 4 + 0] = v.x;
        As[r][q * 4 + 1] = v.y;
        As[r][q * 4 + 2] = v.z;
        As[r][q * 4 + 3] = v.w;
    }
    __syncthreads();
    float acc[16];
#pragma unroll
    for (int i = 0; i < 16; i++) acc[i] = 0.f;
#pragma unroll 4
    for (int k = 0; k < 128; k++) {
        float w = W[k * 128 + col];
#pragma unroll
        for (int i = 0; i < 16; i++) acc[i] += As[half + 2 * i][k] * w;
    }
    float b = bias ? bias[col] : 0.f;
#pragma unroll
    for (int i = 0; i < 16; i++) {
        int gr = row0 + half + 2 * i;
        if (gr < N) C[(size_t)gr * 128 + col] = acc[i] + b;
    }
}

// out[r] += (1/max(cnt,1)) * sum_{j in row r} Y[csrc[j]]; one wave per dst row.
__global__ __launch_bounds__(256) void agg_k(const float* __restrict__ Y,
                                             const int* __restrict__ roff,
                                             const int* __restrict__ csrc, int Nrows,
                                             float* __restrict__ out, int relu) {
    int w = blockIdx.x * 4 + (threadIdx.x >> 6);
    if (w >= Nrows) return;
    int lane = threadIdx.x & 63;
    int o0 = roff[w], o1 = roff[w + 1];
    const float2* Y2 = (const float2*)Y;
    float2 acc = make_float2(0.f, 0.f);
    for (int j = o0; j < o1; j++) {
        int s = csrc[j];
        float2 v = Y2[(size_t)s * 64 + lane];
        acc.x += v.x;
        acc.y += v.y;
    }
    int c = o1 - o0;
    float inv = 1.f / (float)(c > 0 ? c : 1);
    float2* O2 = (float2*)out;
    float2 curv = O2[(size_t)w * 64 + lane];
    curv.x += acc.x * inv;
    curv.y += acc.y * inv;
    if (relu) {
        curv.x = fmaxf(curv.x, 0.f);
        curv.y = fmaxf(curv.y, 0.f);
    }
    O2[(size_t)w * 64 + lane] = curv;
}

// ---------------- launch ----------------

static inline size_t align256(size_t x) { return (x + 255) & ~size_t(255); }

extern "C" void kernel_launch(void* const* d_in, const int* in_sizes, int n_in,
                              void* d_out, int out_size, void* d_ws, size_t ws_size,
                              hipStream_t stream) {
    const float* x_kw = (const float*)d_in[0];
    const float* x_rt = (const float*)d_in[1];
    const int* src_a = (const int*)d_in[2];
    const int* dst_a = (const int*)d_in[3];
    const int* src_b = (const int*)d_in[4];
    const int* dst_b = (const int*)d_in[5];
    const int* src_c = (const int*)d_in[6];
    const int* dst_c = (const int*)d_in[7];
    const float *Wl1a = (const float*)d_in[8],  *bl1a = (const float*)d_in[9],  *Wr1a = (const float*)d_in[10];
    const float *Wl1b = (const float*)d_in[11], *bl1b = (const float*)d_in[12], *Wr1b = (const float*)d_in[13];
    const float *Wl1c = (const float*)d_in[14], *bl1c = (const float*)d_in[15], *Wr1c = (const float*)d_in[16];
    const float *Wl2a = (const float*)d_in[17], *bl2a = (const float*)d_in[18], *Wr2a = (const float*)d_in[19];
    const float *Wl2b = (const float*)d_in[20], *bl2b = (const float*)d_in[21], *Wr2b = (const float*)d_in[22];
    const float *Wl2c = (const float*)d_in[23], *bl2c = (const float*)d_in[24], *Wr2c = (const float*)d_in[25];

    const int NKW = in_sizes[0] / 128;
    const int NRT = in_sizes[1] / 128;
    const int EA = in_sizes[2], EB = in_sizes[4], EC = in_sizes[6];

    char* ws = (char*)d_ws;
    size_t off = 0;
    auto alloc = [&](size_t bytes) -> char* {
        off = align256(off);
        char* p = ws + off;
        off += bytes;
        return p;
    };
    int* roff_a = (int*)alloc((size_t)(NKW + 1) * 4);
    int* roff_b = (int*)alloc((size_t)(NKW + 1) * 4);
    int* roff_c = (int*)alloc((size_t)(NRT + 1) * 4);
    int* cur_a  = (int*)alloc((size_t)NKW * 4);
    int* cur_b  = (int*)alloc((size_t)NKW * 4);
    int* cur_c  = (int*)alloc((size_t)NRT * 4);
    int* bsum   = (int*)alloc(512 * 4);
    int* csr_a  = (int*)alloc((size_t)EA * 4);
    int* csr_b  = (int*)alloc((size_t)EB * 4);
    int* csr_c  = (int*)alloc((size_t)EC * 4);
    float* Wcomb = (float*)alloc(128 * 128 * 4);
    float* bcomb = (float*)alloc(128 * 4);
    float* Ybuf  = (float*)alloc((size_t)NKW * 128 * 4);
    float* kw1   = (float*)alloc((size_t)NKW * 128 * 4);
    float* rt1   = (float*)alloc((size_t)NRT * 128 * 4);
    (void)ws_size;

    float* out_kw = (float*)d_out;
    float* out_rt = out_kw + (size_t)NKW * 128;

    auto build = [&](const int* src, const int* dst, int E, int N, int* roff, int* cur, int* csrc) {
        zero_k<<<(N + 255) / 256, 256, 0, stream>>>(cur, N);
        hist_k<<<(E + 255) / 256, 256, 0, stream>>>(dst, E, cur);
        int nb = (N + 255) / 256;
        scan_pass1<<<nb, 256, 0, stream>>>(cur, N, bsum);
        scan_pass2<<<1, 512, 0, stream>>>(bsum, nb);
        scan_pass3<<<nb, 256, 0, stream>>>(cur, N, bsum, roff);
        zero_k<<<(N + 255) / 256, 256, 0, stream>>>(cur, N);
        scatter_k<<<(E + 255) / 256, 256, 0, stream>>>(src, dst, E, roff, cur, csrc);
    };
    build(src_a, dst_a, EA, NKW, roff_a, cur_a, csr_a);
    build(src_b, dst_b, EB, NKW, roff_b, cur_b, csr_b);
    build(src_c, dst_c, EC, NRT, roff_c, cur_c, csr_c);

    auto gemm = [&](const float* A, int N, const float* W, const float* bias, float* C) {
        gemm128_k<<<(N + 31) / 32, 256, 0, stream>>>(A, N, W, bias, C);
    };
    auto agg = [&](const float* Y, const int* roff_, const int* csrc, int Nrows, float* o, int relu) {
        agg_k<<<(Nrows + 3) / 4, 256, 0, stream>>>(Y, roff_, csrc, Nrows, o, relu);
    };

    // ---- layer 1 ----
    combine_wb_k<<<64, 256, 0, stream>>>(Wr1a, Wr1b, bl1a, bl1b, Wcomb, bcomb);
    gemm(x_kw, NKW, Wcomb, bcomb, kw1);       // Z_kw = x_kw @ (Wr1a+Wr1b) + (bl1a+bl1b)
    gemm(x_rt, NRT, Wl1a, nullptr, Ybuf);     // Y_a = x_rt @ Wl1a
    agg(Ybuf, roff_a, csr_a, NKW, kw1, 0);
    gemm(x_kw, NKW, Wl1b, nullptr, Ybuf);     // Y_b = x_kw @ Wl1b
    agg(Ybuf, roff_b, csr_b, NKW, kw1, 1);    // + ReLU
    gemm(x_rt, NRT, Wr1c, bl1c, rt1);         // Z_rt = x_rt @ Wr1c + bl1c
    gemm(x_rt, NRT, Wl1c, nullptr, Ybuf);     // Y_c = x_rt @ Wl1c
    agg(Ybuf, roff_c, csr_c, NRT, rt1, 1);    // + ReLU

    // ---- layer 2 ----
    combine_wb_k<<<64, 256, 0, stream>>>(Wr2a, Wr2b, bl2a, bl2b, Wcomb, bcomb);
    gemm(kw1, NKW, Wcomb, bcomb, out_kw);     // Z2_kw
    gemm(rt1, NRT, Wl2a, nullptr, Ybuf);      // Y2_a = rt1 @ Wl2a
    agg(Ybuf, roff_a, csr_a, NKW, out_kw, 0);
    gemm(kw1, NKW, Wl2b, nullptr, Ybuf);      // Y2_b = kw1 @ Wl2b
    agg(Ybuf, roff_b, csr_b, NKW, out_kw, 0);
    gemm(rt1, NRT, Wr2c, bl2c, out_rt);       // Z2_rt
    gemm(rt1, NRT, Wl2c, nullptr, Ybuf);      // Y2_c = rt1 @ Wl2c
    agg(Ybuf, roff_c, csr_c, NRT, out_rt, 0);
}

// Round 2
// 1112.881 us; speedup vs baseline: 1.3473x; 1.3473x over previous
//
#include <hip/hip_runtime.h>

typedef __attribute__((ext_vector_type(8))) short bf16x8;
typedef __attribute__((ext_vector_type(4))) float f32x4;

static __device__ __forceinline__ unsigned short f2bf(float f) {
    unsigned int u = __float_as_uint(f);
    u += 0x7fffu + ((u >> 16) & 1u);   // round-to-nearest-even
    return (unsigned short)(u >> 16);
}
static __device__ __forceinline__ float bf2f(unsigned short h) {
    return __uint_as_float(((unsigned int)h) << 16);
}

// ---------------- CSR build kernels ----------------

__global__ void zero_k(int* p, int n) {
    int i = blockIdx.x * 256 + threadIdx.x;
    if (i < n) p[i] = 0;
}

__global__ void hist_k(const int* __restrict__ dst, int E, int* __restrict__ deg) {
    int i = blockIdx.x * 256 + threadIdx.x;
    if (i < E) atomicAdd(&deg[dst[i]], 1);
}

__global__ void scan_pass1(const int* __restrict__ deg, int n, int* __restrict__ bsum) {
    __shared__ int s[256];
    int i = blockIdx.x * 256 + threadIdx.x;
    int v = (i < n) ? deg[i] : 0;
    s[threadIdx.x] = v;
    __syncthreads();
    for (int off = 128; off > 0; off >>= 1) {
        if (threadIdx.x < off) s[threadIdx.x] += s[threadIdx.x + off];
        __syncthreads();
    }
    if (threadIdx.x == 0) bsum[blockIdx.x] = s[0];
}

__global__ void scan_pass2(int* bsum, int nb) {
    __shared__ int s[512];
    int t = threadIdx.x;
    int v = (t < nb) ? bsum[t] : 0;
    s[t] = v;
    __syncthreads();
    for (int off = 1; off < 512; off <<= 1) {
        int x = (t >= off) ? s[t - off] : 0;
        __syncthreads();
        s[t] += x;
        __syncthreads();
    }
    if (t < nb) bsum[t] = s[t] - v;
}

__global__ void scan_pass3(const int* __restrict__ deg, int n, const int* __restrict__ bsum,
                           int* __restrict__ roff) {
    __shared__ int s[256];
    int t = threadIdx.x;
    int i = blockIdx.x * 256 + t;
    int v = (i < n) ? deg[i] : 0;
    s[t] = v;
    __syncthreads();
    for (int off = 1; off < 256; off <<= 1) {
        int x = (t >= off) ? s[t - off] : 0;
        __syncthreads();
        s[t] += x;
        __syncthreads();
    }
    int excl = s[t] - v;
    int res = bsum[blockIdx.x] + excl;
    if (i < n) roff[i] = res;
    if (i == n - 1) roff[n] = res + v;
}

__global__ void scatter_k(const int* __restrict__ src, const int* __restrict__ dst, int E,
                          const int* __restrict__ roff, int* __restrict__ cur,
                          int* __restrict__ csrc) {
    int i = blockIdx.x * 256 + threadIdx.x;
    if (i < E) {
        int d = dst[i];
        int pos = roff[d] + atomicAdd(&cur[d], 1);
        csrc[pos] = src[i];
    }
}

// ---------------- prep kernels ----------------

// transpose + convert 128x128 W (optionally += W2) to bf16 W^T
__global__ void wt_k(const float* __restrict__ W, const float* __restrict__ W2,
                     unsigned short* __restrict__ Wt) {
    int i = blockIdx.x * 256 + threadIdx.x;  // 0..16383
    if (i >= 128 * 128) return;
    int k = i >> 7, n = i & 127;
    float v = W[i];
    if (W2) v += W2[i];
    Wt[n * 128 + k] = f2bf(v);
}

__global__ void bias_comb_k(const float* __restrict__ a, const float* __restrict__ b,
                            float* __restrict__ o) {
    int i = threadIdx.x;
    if (i < 128) o[i] = a[i] + b[i];
}

__global__ void f2bf_vec_k(const float* __restrict__ x, unsigned short* __restrict__ y, int n4) {
    int i = blockIdx.x * 256 + threadIdx.x;
    if (i < n4) {
        float4 v = ((const float4*)x)[i];
        ushort4 o;
        o.x = f2bf(v.x); o.y = f2bf(v.y); o.z = f2bf(v.z); o.w = f2bf(v.w);
        ((ushort4*)y)[i] = o;
    }
}

// ---------------- MFMA GEMM: C[N x 128] = A_bf16[N x 128] @ W (Wt = W^T bf16) ----------------
// Block 256 thr = 4 waves; wave computes 16 rows x 128 cols via 16x16x32 MFMA.
// A-frag: lane l holds A[row0 + (l&15)][kc*32 + (l>>4)*8 + 0..7]
// B-frag: lane l holds W[kc*32 + (l>>4)*8 + 0..7][ct*16 + (l&15)]  (= contiguous in Wt row)
// C/D:    lane l, reg j -> row (l>>4)*4 + j, col l&15   [m89]
template <int OUTBF16>
__global__ __launch_bounds__(256) void gemm_mfma_k(const unsigned short* __restrict__ A, int N,
                                                   const unsigned short* __restrict__ Wt,
                                                   const float* __restrict__ bias,
                                                   float* __restrict__ Cf,
                                                   unsigned short* __restrict__ Cb) {
    int wv = threadIdx.x >> 6, lane = threadIdx.x & 63;
    int r16 = lane & 15, g = lane >> 4;
    int row0 = blockIdx.x * 64 + wv * 16;
    int arow = row0 + r16;
    int arow_c = arow < N ? arow : N - 1;
    const bf16x8* Arow = (const bf16x8*)(A + (size_t)arow_c * 128);

    bf16x8 af[4];
#pragma unroll
    for (int kc = 0; kc < 4; kc++) af[kc] = Arow[kc * 4 + g];

    f32x4 acc[8];
#pragma unroll
    for (int ct = 0; ct < 8; ct++) {
        f32x4 z = {0.f, 0.f, 0.f, 0.f};
        acc[ct] = z;
    }
#pragma unroll
    for (int kc = 0; kc < 4; kc++) {
#pragma unroll
        for (int ct = 0; ct < 8; ct++) {
            bf16x8 bfrag = *(const bf16x8*)(Wt + ((ct * 16 + r16) << 7) + kc * 32 + g * 8);
            acc[ct] = __builtin_amdgcn_mfma_f32_16x16x32_bf16(af[kc], bfrag, acc[ct], 0, 0, 0);
        }
    }
#pragma unroll
    for (int ct = 0; ct < 8; ct++) {
        int col = ct * 16 + r16;
        float b = bias ? bias[col] : 0.f;
#pragma unroll
        for (int j = 0; j < 4; j++) {
            int r = row0 + g * 4 + j;
            if (r < N) {
                float v = acc[ct][j] + b;
                if (OUTBF16) Cb[(size_t)r * 128 + col] = f2bf(v);
                else Cf[(size_t)r * 128 + col] = v;
            }
        }
    }
}

// ---------------- aggregation: out = Zin + mean_{j in row} Y[csrc[j]] ----------------
// One wave per dst row. Lanes split: g = lane>>5 handles edges j = o0+g, o0+g+2, ...
// Each lane loads 8B (4 bf16) of the 256B row; q = lane&31 selects the chunk.
template <int RELU, int OUTBF16>
__global__ __launch_bounds__(256) void agg_k(const unsigned short* __restrict__ Y,
                                             const int* __restrict__ roff,
                                             const int* __restrict__ csrc, int Nrows,
                                             const float* __restrict__ Zin,
                                             float* __restrict__ OutF,
                                             unsigned short* __restrict__ OutB) {
    int w = blockIdx.x * 4 + (threadIdx.x >> 6);
    if (w >= Nrows) return;
    int lane = threadIdx.x & 63;
    int g = lane >> 5;
    int q = lane & 31;
    int o0 = roff[w], o1 = roff[w + 1];
    float a0 = 0.f, a1 = 0.f, a2 = 0.f, a3 = 0.f;
    for (int j = o0 + g; j < o1; j += 2) {
        int s = csrc[j];
        ushort4 v = *(const ushort4*)(Y + (size_t)s * 128 + q * 4);
        a0 += bf2f(v.x);
        a1 += bf2f(v.y);
        a2 += bf2f(v.z);
        a3 += bf2f(v.w);
    }
    a0 += __shfl_down(a0, 32);
    a1 += __shfl_down(a1, 32);
    a2 += __shfl_down(a2, 32);
    a3 += __shfl_down(a3, 32);
    if (lane < 32) {
        int c = o1 - o0;
        float inv = 1.f / (float)(c > 0 ? c : 1);
        const float4 z = *(const float4*)(Zin + (size_t)w * 128 + q * 4);
        float r0 = z.x + a0 * inv;
        float r1 = z.y + a1 * inv;
        float r2 = z.z + a2 * inv;
        float r3 = z.w + a3 * inv;
        if (RELU) {
            r0 = fmaxf(r0, 0.f); r1 = fmaxf(r1, 0.f);
            r2 = fmaxf(r2, 0.f); r3 = fmaxf(r3, 0.f);
        }
        if (OUTBF16) {
            ushort4 o;
            o.x = f2bf(r0); o.y = f2bf(r1); o.z = f2bf(r2); o.w = f2bf(r3);
            *(ushort4*)(OutB + (size_t)w * 128 + q * 4) = o;
        } else {
            float4 o = make_float4(r0, r1, r2, r3);
            *(float4*)(OutF + (size_t)w * 128 + q * 4) = o;
        }
    }
}

// ---------------- launch ----------------

static inline size_t align256(size_t x) { return (x + 255) & ~size_t(255); }

extern "C" void kernel_launch(void* const* d_in, const int* in_sizes, int n_in,
                              void* d_out, int out_size, void* d_ws, size_t ws_size,
                              hipStream_t stream) {
    const float* x_kw = (const float*)d_in[0];
    const float* x_rt = (const float*)d_in[1];
    const int* src_a = (const int*)d_in[2];
    const int* dst_a = (const int*)d_in[3];
    const int* src_b = (const int*)d_in[4];
    const int* dst_b = (const int*)d_in[5];
    const int* src_c = (const int*)d_in[6];
    const int* dst_c = (const int*)d_in[7];
    const float *Wl1a = (const float*)d_in[8],  *bl1a = (const float*)d_in[9],  *Wr1a = (const float*)d_in[10];
    const float *Wl1b = (const float*)d_in[11], *bl1b = (const float*)d_in[12], *Wr1b = (const float*)d_in[13];
    const float *Wl1c = (const float*)d_in[14], *bl1c = (const float*)d_in[15], *Wr1c = (const float*)d_in[16];
    const float *Wl2a = (const float*)d_in[17], *bl2a = (const float*)d_in[18], *Wr2a = (const float*)d_in[19];
    const float *Wl2b = (const float*)d_in[20], *bl2b = (const float*)d_in[21], *Wr2b = (const float*)d_in[22];
    const float *Wl2c = (const float*)d_in[23], *bl2c = (const float*)d_in[24], *Wr2c = (const float*)d_in[25];

    const int NKW = in_sizes[0] / 128;
    const int NRT = in_sizes[1] / 128;
    const int EA = in_sizes[2], EB = in_sizes[4], EC = in_sizes[6];

    char* ws = (char*)d_ws;
    size_t off = 0;
    auto alloc = [&](size_t bytes) -> char* {
        off = align256(off);
        char* p = ws + off;
        off += bytes;
        return p;
    };
    int* roff_a = (int*)alloc((size_t)(NKW + 1) * 4);
    int* roff_b = (int*)alloc((size_t)(NKW + 1) * 4);
    int* roff_c = (int*)alloc((size_t)(NRT + 1) * 4);
    int* cur_a  = (int*)alloc((size_t)NKW * 4);
    int* cur_b  = (int*)alloc((size_t)NKW * 4);
    int* cur_c  = (int*)alloc((size_t)NRT * 4);
    int* bsum   = (int*)alloc(512 * 4);
    int* csr_a  = (int*)alloc((size_t)EA * 4);
    int* csr_b  = (int*)alloc((size_t)EB * 4);
    int* csr_c  = (int*)alloc((size_t)EC * 4);
    unsigned short* Wt   = (unsigned short*)alloc(10 * 128 * 128 * 2);
    float* bc1   = (float*)alloc(128 * 4);
    float* bc2   = (float*)alloc(128 * 4);
    unsigned short* xkw_bf = (unsigned short*)alloc((size_t)NKW * 128 * 2);
    unsigned short* xrt_bf = (unsigned short*)alloc((size_t)NRT * 128 * 2);
    unsigned short* Ybuf   = (unsigned short*)alloc((size_t)NKW * 128 * 2);
    (void)ws_size;
    // aliases: layer-1 activations overwrite the raw bf16 inputs (dead by then)
    unsigned short* kw1_bf = xkw_bf;
    unsigned short* rt1_bf = xrt_bf;

    float* out_kw = (float*)d_out;
    float* out_rt = out_kw + (size_t)NKW * 128;

    auto build = [&](const int* src, const int* dst, int E, int N, int* roff, int* cur, int* csrc) {
        zero_k<<<(N + 255) / 256, 256, 0, stream>>>(cur, N);
        hist_k<<<(E + 255) / 256, 256, 0, stream>>>(dst, E, cur);
        int nb = (N + 255) / 256;
        scan_pass1<<<nb, 256, 0, stream>>>(cur, N, bsum);
        scan_pass2<<<1, 512, 0, stream>>>(bsum, nb);
        scan_pass3<<<nb, 256, 0, stream>>>(cur, N, bsum, roff);
        zero_k<<<(N + 255) / 256, 256, 0, stream>>>(cur, N);
        scatter_k<<<(E + 255) / 256, 256, 0, stream>>>(src, dst, E, roff, cur, csrc);
    };
    build(src_a, dst_a, EA, NKW, roff_a, cur_a, csr_a);
    build(src_b, dst_b, EB, NKW, roff_b, cur_b, csr_b);
    build(src_c, dst_c, EC, NRT, roff_c, cur_c, csr_c);

    // weight prep: Wt[i] slots
    unsigned short* W0 = Wt + 0 * 16384;  // Wr1a+Wr1b ^T
    unsigned short* W1 = Wt + 1 * 16384;  // Wl1a ^T
    unsigned short* W2 = Wt + 2 * 16384;  // Wl1b ^T
    unsigned short* W3 = Wt + 3 * 16384;  // Wl1c ^T
    unsigned short* W4 = Wt + 4 * 16384;  // Wr1c ^T
    unsigned short* W5 = Wt + 5 * 16384;  // Wr2a+Wr2b ^T
    unsigned short* W6 = Wt + 6 * 16384;  // Wl2a ^T
    unsigned short* W7 = Wt + 7 * 16384;  // Wl2b ^T
    unsigned short* W8 = Wt + 8 * 16384;  // Wl2c ^T
    unsigned short* W9 = Wt + 9 * 16384;  // Wr2c ^T
    wt_k<<<64, 256, 0, stream>>>(Wr1a, Wr1b, W0);
    wt_k<<<64, 256, 0, stream>>>(Wl1a, nullptr, W1);
    wt_k<<<64, 256, 0, stream>>>(Wl1b, nullptr, W2);
    wt_k<<<64, 256, 0, stream>>>(Wl1c, nullptr, W3);
    wt_k<<<64, 256, 0, stream>>>(Wr1c, nullptr, W4);
    wt_k<<<64, 256, 0, stream>>>(Wr2a, Wr2b, W5);
    wt_k<<<64, 256, 0, stream>>>(Wl2a, nullptr, W6);
    wt_k<<<64, 256, 0, stream>>>(Wl2b, nullptr, W7);
    wt_k<<<64, 256, 0, stream>>>(Wl2c, nullptr, W8);
    wt_k<<<64, 256, 0, stream>>>(Wr2c, nullptr, W9);
    bias_comb_k<<<1, 128, 0, stream>>>(bl1a, bl1b, bc1);
    bias_comb_k<<<1, 128, 0, stream>>>(bl2a, bl2b, bc2);

    // input conversion
    {
        int n4 = NKW * 32;
        f2bf_vec_k<<<(n4 + 255) / 256, 256, 0, stream>>>(x_kw, xkw_bf, n4);
        n4 = NRT * 32;
        f2bf_vec_k<<<(n4 + 255) / 256, 256, 0, stream>>>(x_rt, xrt_bf, n4);
    }

    auto gemm_f = [&](const unsigned short* A, int N, const unsigned short* Wt_,
                      const float* bias, float* C) {
        gemm_mfma_k<0><<<(N + 63) / 64, 256, 0, stream>>>(A, N, Wt_, bias, C, nullptr);
    };
    auto gemm_b = [&](const unsigned short* A, int N, const unsigned short* Wt_,
                      unsigned short* C) {
        gemm_mfma_k<1><<<(N + 63) / 64, 256, 0, stream>>>(A, N, Wt_, nullptr, nullptr, C);
    };
    auto agg_acc = [&](const unsigned short* Y, const int* roff_, const int* csrc, int Nr,
                       float* zio) {
        agg_k<0, 0><<<(Nr + 3) / 4, 256, 0, stream>>>(Y, roff_, csrc, Nr, zio, zio, nullptr);
    };
    auto agg_fin = [&](const unsigned short* Y, const int* roff_, const int* csrc, int Nr,
                       const float* zin, unsigned short* ob) {
        agg_k<1, 1><<<(Nr + 3) / 4, 256, 0, stream>>>(Y, roff_, csrc, Nr, zin, nullptr, ob);
    };

    // ---- layer 1 ----  (kw accum lives in out_kw, rt accum in out_rt; finalized to bf16)
    gemm_f(xkw_bf, NKW, W0, bc1, out_kw);            // Z_kw
    gemm_b(xrt_bf, NRT, W1, Ybuf);                   // Y_a = x_rt @ Wl1a
    agg_acc(Ybuf, roff_a, csr_a, NKW, out_kw);
    gemm_b(xkw_bf, NKW, W2, Ybuf);                   // Y_b = x_kw @ Wl1b
    agg_fin(Ybuf, roff_b, csr_b, NKW, out_kw, kw1_bf);  // + relu -> kw1 (bf16)
    gemm_f(xrt_bf, NRT, W4, bl1c, out_rt);           // Z_rt
    gemm_b(xrt_bf, NRT, W3, Ybuf);                   // Y_c = x_rt @ Wl1c
    agg_fin(Ybuf, roff_c, csr_c, NRT, out_rt, rt1_bf);  // + relu -> rt1 (bf16)

    // ---- layer 2 ----
    gemm_f(kw1_bf, NKW, W5, bc2, out_kw);            // Z2_kw
    gemm_b(rt1_bf, NRT, W6, Ybuf);                   // Y2_a = rt1 @ Wl2a
    agg_acc(Ybuf, roff_a, csr_a, NKW, out_kw);
    gemm_b(kw1_bf, NKW, W7, Ybuf);                   // Y2_b = kw1 @ Wl2b
    agg_acc(Ybuf, roff_b, csr_b, NKW, out_kw);
    gemm_f(rt1_bf, NRT, W9, bl2c, out_rt);           // Z2_rt
    gemm_b(rt1_bf, NRT, W8, Ybuf);                   // Y2_c = rt1 @ Wl2c
    agg_acc(Ybuf, roff_c, csr_c, NRT, out_rt);
}